// Round 1
// baseline (2013.060 us; speedup 1.0000x reference)
//
#include <hip/hip_runtime.h>

// Problem constants
#define NN 128
#define CC 64          // C_IN == C_OUT
#define TT 256
#define VV 25
#define NSUB 3
#define TCH 16                 // t-rows per block tile
#define LPOS (TCH*VV)          // 400 positions per block tile
#define NCHUNK (TT/TCH)        // 16 chunks per n
#define CNT (NN*TT*VV)         // 819200 positions per channel

// workspace layout (float offsets)
#define WS_BEFF 80      // 64:  b_eff
#define WS_GSUM 144     // 64:  global sum of y (hidden minus bias)
#define WS_GSQ  208     // 64:  global sum of y^2
#define WS_W    320     // 25*64*64: W_eff then (in-place) M_fin, [v][c][o]; byte 1280 -> 256B-aligned rows
#define WS_BFIN (WS_W + VV*CC*CC)   // 64: folded bias  (total ~411 KB)

// fused: rowsums (in LDS), W_eff build, b_eff, and gsum/gsq zeroing
__global__ void k_weff(const float* __restrict__ A, const float* __restrict__ ga,
                       const float* __restrict__ gw, const float* __restrict__ gb,
                       float* __restrict__ ws) {
    __shared__ float S[NSUB*VV];
    int tid = threadIdx.x;
    if (tid < NSUB*VV) {
        int i = tid / VV, v = tid % VV;
        const float* pa = A  + (i*VV + v)*VV;
        const float* pg = ga + (i*VV + v)*VV;
        float s = 0.f;
        for (int w2 = 0; w2 < VV; ++w2) s += pa[w2] + pg[w2];
        S[tid] = s;
    }
    __syncthreads();
    int idx = blockIdx.x*256 + tid;
    int v = idx >> 12;
    int c = (idx >> 6) & 63;
    int o = idx & 63;
    float acc = 0.f;
    #pragma unroll
    for (int i = 0; i < NSUB; ++i)
        acc = fmaf(gw[(i*CC + o)*CC + c], 1.f + S[i*VV + v], acc);
    ws[WS_W + idx] = acc;
    if (blockIdx.x == 0 && tid < CC)
        ws[WS_BEFF + tid] = gb[tid] + gb[CC + tid] + gb[2*CC + tid];
    if (blockIdx.x == 1 && tid < 128)
        ws[WS_GSUM + tid] = 0.f;   // zeros gsum(64)+gsq(64), contiguous
}

// Shared GEMM tile: per block (n, 16-t chunk, all 25 v).
// Wave-uniform v: wave w handles v = w+4k (k<7). Lane: og=lane&3 (o=og*16+oi), tl=lane>>2 (t=tl).
// Two c-halves of 32 through one 51.2KB LDS buffer; acc[7][16] persists in regs.
// W loads: 4x float4/lane from one 256B-aligned row -> ~2 txns/instr (vs ~50 in the old v-in-lane map).
__device__ __forceinline__ void gemm_tile(const float* __restrict__ xb,
                                          const float* __restrict__ wmat,
                                          float* __restrict__ Xs,
                                          float acc[7][16],
                                          int tid, int w, int og, int tl) {
    #pragma unroll
    for (int k = 0; k < 7; ++k)
        #pragma unroll
        for (int oi = 0; oi < 16; ++oi) acc[k][oi] = 0.f;
    for (int half = 0; half < 2; ++half) {
        __syncthreads();
        for (int i4 = tid; i4 < 32*(LPOS/4); i4 += 256) {
            int c = i4 / (LPOS/4), j = i4 - c*(LPOS/4);
            *(float4*)&Xs[c*LPOS + j*4] = *(const float4*)(xb + (half*32 + c)*(TT*VV) + j*4);
        }
        __syncthreads();
        #pragma unroll
        for (int k = 0; k < 7; ++k) {
            int v = w + 4*k;
            if (v < VV) {                      // wave-uniform branch
                const float* wp = wmat + ((size_t)v*CC + half*32)*CC + og*16;
                const float* xp = Xs + tl*VV + v;
                #pragma unroll 4
                for (int c = 0; c < 32; ++c) {
                    float xx = xp[c*LPOS];     // 1 b32, 16 distinct banks, og-broadcast
                    float4 wq0 = *(const float4*)(wp + c*CC);
                    float4 wq1 = *(const float4*)(wp + c*CC + 4);
                    float4 wq2 = *(const float4*)(wp + c*CC + 8);
                    float4 wq3 = *(const float4*)(wp + c*CC + 12);
                    acc[k][0]  = fmaf(xx, wq0.x, acc[k][0]);
                    acc[k][1]  = fmaf(xx, wq0.y, acc[k][1]);
                    acc[k][2]  = fmaf(xx, wq0.z, acc[k][2]);
                    acc[k][3]  = fmaf(xx, wq0.w, acc[k][3]);
                    acc[k][4]  = fmaf(xx, wq1.x, acc[k][4]);
                    acc[k][5]  = fmaf(xx, wq1.y, acc[k][5]);
                    acc[k][6]  = fmaf(xx, wq1.z, acc[k][6]);
                    acc[k][7]  = fmaf(xx, wq1.w, acc[k][7]);
                    acc[k][8]  = fmaf(xx, wq2.x, acc[k][8]);
                    acc[k][9]  = fmaf(xx, wq2.y, acc[k][9]);
                    acc[k][10] = fmaf(xx, wq2.z, acc[k][10]);
                    acc[k][11] = fmaf(xx, wq2.w, acc[k][11]);
                    acc[k][12] = fmaf(xx, wq3.x, acc[k][12]);
                    acc[k][13] = fmaf(xx, wq3.y, acc[k][13]);
                    acc[k][14] = fmaf(xx, wq3.z, acc[k][14]);
                    acc[k][15] = fmaf(xx, wq3.w, acc[k][15]);
                }
            }
        }
    }
}

__global__ __launch_bounds__(256, 2) void k_stats(const float* __restrict__ x,
                                                  const float* __restrict__ ws,
                                                  float* __restrict__ gsum,
                                                  float* __restrict__ gsq) {
    __shared__ __align__(16) float Xs[32*LPOS];
    __shared__ float s_sum[CC], s_sq[CC];
    int tid = threadIdx.x;
    int lane = tid & 63, w = tid >> 6;
    int og = lane & 3, tl = lane >> 2;
    int n = blockIdx.x >> 4, ch = blockIdx.x & 15;
    const float* xb = x + (size_t)n*(CC*TT*VV) + ch*LPOS;
    if (tid < CC) { s_sum[tid] = 0.f; s_sq[tid] = 0.f; }
    float acc[7][16];
    gemm_tile(xb, ws + WS_W, Xs, acc, tid, w, og, tl);
    // per-lane partials over this lane's (t, v-list) for its 16 o's
    float rs[16], rsq[16];
    #pragma unroll
    for (int oi = 0; oi < 16; ++oi) { rs[oi] = 0.f; rsq[oi] = 0.f; }
    #pragma unroll
    for (int k = 0; k < 7; ++k) {
        if (w + 4*k < VV) {
            #pragma unroll
            for (int oi = 0; oi < 16; ++oi) {
                rs[oi]  += acc[k][oi];
                rsq[oi]  = fmaf(acc[k][oi], acc[k][oi], rsq[oi]);
            }
        }
    }
    // butterfly reduce over tl (lane bits 2..5); og bits untouched
    #pragma unroll
    for (int m = 4; m <= 32; m <<= 1) {
        #pragma unroll
        for (int oi = 0; oi < 16; ++oi) {
            rs[oi]  += __shfl_xor(rs[oi],  m);
            rsq[oi] += __shfl_xor(rsq[oi], m);
        }
    }
    if (tl == 0) {
        #pragma unroll
        for (int oi = 0; oi < 16; ++oi) {
            atomicAdd(&s_sum[og*16 + oi], rs[oi]);
            atomicAdd(&s_sq[og*16 + oi],  rsq[oi]);
        }
    }
    __syncthreads();
    if (tid < CC) {
        atomicAdd(&gsum[tid], s_sum[tid]);
        atomicAdd(&gsq[tid],  s_sq[tid]);
    }
}

// fold BN into the matrix in-place: M = alpha*W_eff + I; b_fin = beta + alpha*(b_eff - mean)
__global__ void k_mid(float* __restrict__ ws, const float* __restrict__ gamma,
                      const float* __restrict__ beta) {
    int idx = blockIdx.x*256 + threadIdx.x;
    int c = (idx >> 6) & 63;
    int o = idx & 63;
    float b     = ws[WS_BEFF + o];
    float meanY = ws[WS_GSUM + o] * (1.f/CNT);
    float ey2   = ws[WS_GSQ  + o] * (1.f/CNT);
    float m   = meanY + b;                          // E[hidden]
    float var = ey2 + 2.f*b*meanY + b*b - m*m;      // biased variance
    float alpha = gamma[o] * rsqrtf(var + 1e-5f);
    float wv = ws[WS_W + idx];
    ws[WS_W + idx] = fmaf(alpha, wv, (c == o) ? 1.f : 0.f);  // fold identity residual
    if (blockIdx.x == 0 && threadIdx.x < CC)
        ws[WS_BFIN + o] = fmaf(alpha, b - m, beta[o]);
}

__global__ __launch_bounds__(256, 2) void k_final(const float* __restrict__ x,
                                                  const float* __restrict__ ws,
                                                  float* __restrict__ out) {
    __shared__ __align__(16) float Xs[32*LPOS];
    int tid = threadIdx.x;
    int lane = tid & 63, w = tid >> 6;
    int og = lane & 3, tl = lane >> 2;
    int n = blockIdx.x >> 4, ch = blockIdx.x & 15;
    const float* xb = x + (size_t)n*(CC*TT*VV) + ch*LPOS;
    float acc[7][16];
    gemm_tile(xb, ws + WS_W, Xs, acc, tid, w, og, tl);
    float bf[16];
    #pragma unroll
    for (int oi = 0; oi < 16; ++oi) bf[oi] = ws[WS_BFIN + og*16 + oi];
    float* ob = out + (size_t)n*(CC*TT*VV) + ch*LPOS;
    // reshuffle through LDS (Xs dead) -> coalesced float4 stores, two o-halves
    #pragma unroll
    for (int r = 0; r < 2; ++r) {
        __syncthreads();
        if ((og >> 1) == r) {
            int ol = (og & 1) * 16;
            #pragma unroll
            for (int k = 0; k < 7; ++k) {
                int v = w + 4*k;
                if (v < VV) {
                    #pragma unroll
                    for (int oi = 0; oi < 16; ++oi) {
                        float val = fmaxf(acc[k][oi] + bf[oi], 0.f);
                        Xs[(ol + oi)*LPOS + tl*VV + v] = val;
                    }
                }
            }
        }
        __syncthreads();
        for (int i4 = tid; i4 < 32*(LPOS/4); i4 += 256) {
            int o = i4 / (LPOS/4), j = i4 - o*(LPOS/4);
            *(float4*)(ob + (r*32 + o)*(TT*VV) + j*4) = *(const float4*)&Xs[o*LPOS + j*4];
        }
    }
}

extern "C" void kernel_launch(void* const* d_in, const int* in_sizes, int n_in,
                              void* d_out, int out_size, void* d_ws, size_t ws_size,
                              hipStream_t stream) {
    const float* x     = (const float*)d_in[0];
    const float* A     = (const float*)d_in[1];
    const float* ga    = (const float*)d_in[2];
    // d_in[3..6] = a_w, a_b, b_w, b_b: provably unused (softmax over contracted axis sums to 1)
    const float* gw    = (const float*)d_in[7];
    const float* gb    = (const float*)d_in[8];
    const float* gamma = (const float*)d_in[9];
    const float* beta  = (const float*)d_in[10];
    float* ws  = (float*)d_ws;
    float* out = (float*)d_out;

    hipLaunchKernelGGL(k_weff,  dim3(400), dim3(256), 0, stream, A, ga, gw, gb, ws);
    hipLaunchKernelGGL(k_stats, dim3(NN*NCHUNK), dim3(256), 0, stream,
                       x, ws, ws + WS_GSUM, ws + WS_GSQ);
    hipLaunchKernelGGL(k_mid,   dim3(400), dim3(256), 0, stream, ws, gamma, beta);
    hipLaunchKernelGGL(k_final, dim3(NN*NCHUNK), dim3(256), 0, stream, x, ws, out);
}

// Round 2
// 1117.096 us; speedup vs baseline: 1.8020x; 1.8020x over previous
//
#include <hip/hip_runtime.h>

// Problem constants
#define NN 128
#define CC 64          // C_IN == C_OUT
#define TT 256
#define VV 25
#define NSUB 3
#define TCH 8                  // t-rows per block tile
#define LPOS (TCH*VV)          // 200 positions per block tile
#define NCHUNK (TT/TCH)        // 32 chunks per n
#define CNT (NN*TT*VV)         // 819200 positions per channel

// workspace layout (float offsets)
#define WS_BEFF 80      // 64:  b_eff
#define WS_GSUM 144     // 64:  global sum of y (hidden minus bias)
#define WS_GSQ  208     // 64:  global sum of y^2
#define WS_W    320     // 25*64*64: W_eff then (in-place) M_fin, [v][c][o]; 256B-aligned rows
#define WS_BFIN (WS_W + VV*CC*CC)   // 64: folded bias

// 8 FMAs of one x scalar against a W float4-pair
#define FMA8(xx, q0, q1) \
    acc[0]=fmaf(xx,(q0).x,acc[0]); acc[1]=fmaf(xx,(q0).y,acc[1]); \
    acc[2]=fmaf(xx,(q0).z,acc[2]); acc[3]=fmaf(xx,(q0).w,acc[3]); \
    acc[4]=fmaf(xx,(q1).x,acc[4]); acc[5]=fmaf(xx,(q1).y,acc[5]); \
    acc[6]=fmaf(xx,(q1).z,acc[6]); acc[7]=fmaf(xx,(q1).w,acc[7]);

// fused: rowsums (in LDS), W_eff build, b_eff, and gsum/gsq zeroing
__global__ void k_weff(const float* __restrict__ A, const float* __restrict__ ga,
                       const float* __restrict__ gw, const float* __restrict__ gb,
                       float* __restrict__ ws) {
    __shared__ float S[NSUB*VV];
    int tid = threadIdx.x;
    if (tid < NSUB*VV) {
        int i = tid / VV, v = tid % VV;
        const float* pa = A  + (i*VV + v)*VV;
        const float* pg = ga + (i*VV + v)*VV;
        float s = 0.f;
        for (int w2 = 0; w2 < VV; ++w2) s += pa[w2] + pg[w2];
        S[tid] = s;
    }
    __syncthreads();
    int idx = blockIdx.x*256 + tid;
    int v = idx >> 12;
    int c = (idx >> 6) & 63;
    int o = idx & 63;
    float acc = 0.f;
    #pragma unroll
    for (int i = 0; i < NSUB; ++i)
        acc = fmaf(gw[(i*CC + o)*CC + c], 1.f + S[i*VV + v], acc);
    ws[WS_W + idx] = acc;
    if (blockIdx.x == 0 && tid < CC)
        ws[WS_BEFF + tid] = gb[tid] + gb[CC + tid] + gb[2*CC + tid];
    if (blockIdx.x == 1 && tid < 128)
        ws[WS_GSUM + tid] = 0.f;   // zeros gsum(64)+gsq(64), contiguous
}

// Heavy pass structure (k_stats / k_final):
//   block = (n, 8-t chunk); Xs[c][tl*25+v] staged exactly as the proven r0 kernel.
//   wave w serially owns v = w+4k (wave-uniform -> W reads hit ONE 256B row).
//   lane: og=lane>>3 (8 o's, held as acc[8]), tl=lane&7 (t). W reused across 8 t
//   by the 8 lanes sharing og (same cache line), and across o in registers.
__global__ __launch_bounds__(256, 3) void k_stats(const float* __restrict__ x,
                                                  const float* __restrict__ wsw,
                                                  float* __restrict__ gsum,
                                                  float* __restrict__ gsq) {
    __shared__ __align__(16) float Xs[CC*LPOS];
    __shared__ float s_sum[CC], s_sq[CC];
    int tid = threadIdx.x;
    int w = tid >> 6, lane = tid & 63;
    int og = lane >> 3, tl = lane & 7;
    int n = blockIdx.x >> 5, ch = blockIdx.x & 31;
    const float* xb = x + (size_t)n*(CC*TT*VV) + ch*LPOS;
    if (tid < CC) { s_sum[tid] = 0.f; s_sq[tid] = 0.f; }
    for (int i4 = tid; i4 < CC*(LPOS/4); i4 += 256) {
        int c = i4 / (LPOS/4), j4 = i4 - c*(LPOS/4);
        *(float4*)&Xs[c*LPOS + j4*4] = *(const float4*)(xb + c*(TT*VV) + j4*4);
    }
    __syncthreads();
    float rs[8], rsq[8];
    #pragma unroll
    for (int oi = 0; oi < 8; ++oi) { rs[oi] = 0.f; rsq[oi] = 0.f; }
    for (int k = 0; k < 7; ++k) {
        int v = w + 4*k;
        if (v >= VV) break;                       // wave-uniform
        const float* wp = wsw + v*(CC*CC) + og*8;
        const float* xp = Xs + tl*VV + v;
        float acc[8] = {0.f,0.f,0.f,0.f,0.f,0.f,0.f,0.f};
        #pragma unroll 2
        for (int c = 0; c < CC; c += 2) {
            float xa = xp[c*LPOS];
            float xb2 = xp[c*LPOS + LPOS];
            float4 w0 = *(const float4*)(wp + c*CC);
            float4 w1 = *(const float4*)(wp + c*CC + 4);
            float4 w2 = *(const float4*)(wp + c*CC + CC);
            float4 w3 = *(const float4*)(wp + c*CC + CC + 4);
            FMA8(xa, w0, w1)
            FMA8(xb2, w2, w3)
        }
        #pragma unroll
        for (int oi = 0; oi < 8; ++oi) {
            rs[oi] += acc[oi];
            rsq[oi] = fmaf(acc[oi], acc[oi], rsq[oi]);
        }
    }
    // reduce over tl (lane bits 0..2); og bits untouched
    #pragma unroll
    for (int m = 1; m <= 4; m <<= 1) {
        #pragma unroll
        for (int oi = 0; oi < 8; ++oi) {
            rs[oi]  += __shfl_xor(rs[oi],  m);
            rsq[oi] += __shfl_xor(rsq[oi], m);
        }
    }
    if (tl == 0) {
        #pragma unroll
        for (int oi = 0; oi < 8; ++oi) {
            atomicAdd(&s_sum[og*8 + oi], rs[oi]);
            atomicAdd(&s_sq[og*8 + oi],  rsq[oi]);
        }
    }
    __syncthreads();
    if (tid < CC) {
        atomicAdd(&gsum[tid], s_sum[tid]);
        atomicAdd(&gsq[tid],  s_sq[tid]);
    }
}

// fold BN into the matrix in-place: M = alpha*W_eff + I; b_fin = beta + alpha*(b_eff - mean)
__global__ void k_mid(float* __restrict__ ws, const float* __restrict__ gamma,
                      const float* __restrict__ beta) {
    int idx = blockIdx.x*256 + threadIdx.x;
    int c = (idx >> 6) & 63;
    int o = idx & 63;
    float b     = ws[WS_BEFF + o];
    float meanY = ws[WS_GSUM + o] * (1.f/CNT);
    float ey2   = ws[WS_GSQ  + o] * (1.f/CNT);
    float m   = meanY + b;                          // E[hidden]
    float var = ey2 + 2.f*b*meanY + b*b - m*m;      // biased variance
    float alpha = gamma[o] * rsqrtf(var + 1e-5f);
    float wv = ws[WS_W + idx];
    ws[WS_W + idx] = fmaf(alpha, wv, (c == o) ? 1.f : 0.f);  // fold identity residual
    if (blockIdx.x == 0 && threadIdx.x < CC)
        ws[WS_BFIN + o] = fmaf(alpha, b - m, beta[o]);
}

__global__ __launch_bounds__(256, 3) void k_final(const float* __restrict__ x,
                                                  const float* __restrict__ ws,
                                                  float* __restrict__ out) {
    __shared__ __align__(16) float Xs[CC*LPOS];
    int tid = threadIdx.x;
    int w = tid >> 6, lane = tid & 63;
    int og = lane >> 3, tl = lane & 7;
    int n = blockIdx.x >> 5, ch = blockIdx.x & 31;
    const float* xb = x + (size_t)n*(CC*TT*VV) + ch*LPOS;
    float bf[8];
    #pragma unroll
    for (int oi = 0; oi < 8; ++oi) bf[oi] = ws[WS_BFIN + og*8 + oi];
    for (int i4 = tid; i4 < CC*(LPOS/4); i4 += 256) {
        int c = i4 / (LPOS/4), j4 = i4 - c*(LPOS/4);
        *(float4*)&Xs[c*LPOS + j4*4] = *(const float4*)(xb + c*(TT*VV) + j4*4);
    }
    __syncthreads();
    for (int k = 0; k < 7; ++k) {
        int v = w + 4*k;
        if (v >= VV) break;                       // wave-uniform
        const float* wp = ws + WS_W + v*(CC*CC) + og*8;
        const float* xp = Xs + tl*VV + v;
        float acc[8] = {0.f,0.f,0.f,0.f,0.f,0.f,0.f,0.f};
        #pragma unroll 2
        for (int c = 0; c < CC; c += 2) {
            float xa = xp[c*LPOS];
            float xb2 = xp[c*LPOS + LPOS];
            float4 w0 = *(const float4*)(wp + c*CC);
            float4 w1 = *(const float4*)(wp + c*CC + 4);
            float4 w2 = *(const float4*)(wp + c*CC + CC);
            float4 w3 = *(const float4*)(wp + c*CC + CC + 4);
            FMA8(xa, w0, w1)
            FMA8(xb2, w2, w3)
        }
        // write y back in-place into the (now dead) x-column v of Xs.
        // Column v is owned exclusively by this wave -> no race, no barrier.
        float* yp = Xs + tl*VV + v;
        #pragma unroll
        for (int oi = 0; oi < 8; ++oi)
            yp[(og*8 + oi)*LPOS] = fmaxf(acc[oi] + bf[oi], 0.f);
    }
    __syncthreads();
    // coalesced float4 readout: Xs rows now hold y[o][tl*25+v]
    float* ob = out + (size_t)n*(CC*TT*VV) + ch*LPOS;
    for (int i4 = tid; i4 < CC*(LPOS/4); i4 += 256) {
        int o = i4 / (LPOS/4), j4 = i4 - o*(LPOS/4);
        *(float4*)(ob + o*(TT*VV) + j4*4) = *(const float4*)&Xs[o*LPOS + j4*4];
    }
}

extern "C" void kernel_launch(void* const* d_in, const int* in_sizes, int n_in,
                              void* d_out, int out_size, void* d_ws, size_t ws_size,
                              hipStream_t stream) {
    const float* x     = (const float*)d_in[0];
    const float* A     = (const float*)d_in[1];
    const float* ga    = (const float*)d_in[2];
    // d_in[3..6] = a_w, a_b, b_w, b_b: provably unused (softmax over contracted axis sums to 1)
    const float* gw    = (const float*)d_in[7];
    const float* gb    = (const float*)d_in[8];
    const float* gamma = (const float*)d_in[9];
    const float* beta  = (const float*)d_in[10];
    float* ws  = (float*)d_ws;
    float* out = (float*)d_out;

    hipLaunchKernelGGL(k_weff,  dim3(400), dim3(256), 0, stream, A, ga, gw, gb, ws);
    hipLaunchKernelGGL(k_stats, dim3(NN*NCHUNK), dim3(256), 0, stream,
                       x, ws + WS_W, ws + WS_GSUM, ws + WS_GSQ);
    hipLaunchKernelGGL(k_mid,   dim3(400), dim3(256), 0, stream, ws, gamma, beta);
    hipLaunchKernelGGL(k_final, dim3(NN*NCHUNK), dim3(256), 0, stream, x, ws, out);
}